// Round 4
// baseline (15059.923 us; speedup 1.0000x reference)
//
#include <hip/hip_runtime.h>
#include <hip/hip_fp16.h>
#include <math.h>

constexpr int B_ = 16;
constexpr int D_ = 512;
constexpr int N_ = 2048;
constexpr int S_ = 15;
constexpr int TOPK = 16;

// GEMM tiling: block = 64 rows x 512-col chunks (4 chunks), K in 64 tiles of 8.
// Thread tile 8x16. 512 blocks = exactly 2 resident per CU.
constexpr int RT = 64;
constexpr int CT = 512;
constexpr int KT = 8;
constexpr int NCH = N_ / CT;    // 4
constexpr int NKT = D_ / KT;    // 64
constexpr int SCW = 132;        // per-wave slice row stride (128 + 4 pad)

// async global->LDS, 16 bytes per lane (dest = wave-uniform base + lane*16)
__device__ __forceinline__ void gl_lds16(const float* g, float* s) {
    __builtin_amdgcn_global_load_lds(
        (const __attribute__((address_space(1))) unsigned int*)g,
        (__attribute__((address_space(3))) unsigned int*)s,
        16, 0, 0);
}

// ---------------------------------------------------------------------------
// Fused fp32 GEMM: logits -> (E=exp(l) fp16 dump, per-row Z, per-row sorted
// top-16 adjusted by -log Z). Grid (32 rowblocks, 16 batches), 256 threads.
// Epilogue is barrier-free: wave w owns rows [w*16, w*16+16) via a private
// LDS slice buffer; stats threads keep a FIXED global row across all chunks.
// ---------------------------------------------------------------------------
__global__ __launch_bounds__(256, 2) void gemm4(
    const float* __restrict__ srcE, const float* __restrict__ tgtE,
    float* __restrict__ rzbuf,            // [B][N] 1/Z
    float* __restrict__ topv,             // [B][N][16] sorted desc, adjusted (l - logZ)
    int*   __restrict__ topc,             // [B][N][16]
    __half* __restrict__ lhalf)           // [B][N][N] E = exp(l)
{
    // layout (floats): sA [0,1024) 2x8x64 | sB [1024,9216) 2x8x512 | sC [9216,17664) 4x16x132
    __shared__ __align__(16) float smem[17664];   // 69.0 KB -> 2 blocks/CU
    float* sA = smem;
    float* sB = smem + 1024;
    float* sC = smem + 9216;

    const int tid = threadIdx.x;
    const int b  = blockIdx.y;
    const int s0 = blockIdx.x * RT;
    const int w    = tid >> 6, lane = tid & 63;
    const int ty   = tid >> 5, tx = tid & 31;     // GEMM: rows ty*8..+7, cols tx*4 + j*128
    const int ty8  = ty * 8,  tx4 = tx * 4;
    const int sr   = lane >> 2, q = lane & 3;     // stats: global row s0+w*16+sr, col strip q
    const float scale = 0.044194173824159216f;    // 1/sqrt(512)

    const float* gsrc = srcE + (size_t)b * D_ * N_;
    const float* gtgt = tgtE + (size_t)b * D_ * N_;
    float* sCw = &sC[w * 16 * SCW];               // wave-private 16x132 slice buffer

    float z_loc = 0.f;
    float tv[TOPK];
    int   tc16[TOPK];
    float tmin = -1e30f; int tminslot = 0, tmincol = 0x7fffffff;
    #pragma unroll
    for (int k = 0; k < TOPK; k++) { tv[k] = -1e30f; tc16[k] = 0x7fffffff; }

    // ---- async staging: A-tile 8x64 (2 wave-instrs), B-tile 8x512 (16) ----
    auto stage = [&](int bi, int k0, int c0) {
        if (w < 2) {  // A: instr w covers k-rows w*4..w*4+3
            int kr = w * 4 + (lane >> 4);
            gl_lds16(gsrc + (size_t)(k0 + kr) * N_ + s0 + (lane & 15) * 4,
                     &sA[bi * 512 + w * 256]);
        }
        #pragma unroll
        for (int i = 0; i < 4; i++) {  // B: 16 instrs, idx = w*4+i -> (krow, col-half)
            int idx = w * 4 + i;
            int kr = idx >> 1, h = idx & 1;
            gl_lds16(gtgt + (size_t)(k0 + kr) * N_ + c0 + h * 256 + lane * 4,
                     &sB[bi * 4096 + kr * 512 + h * 256]);
        }
    };

    stage(0, 0, 0);

    for (int ch = 0; ch < NCH; ch++) {
        const int c0 = ch * CT;
        float acc[8][16];
        #pragma unroll
        for (int i = 0; i < 8; i++)
            #pragma unroll
            for (int j = 0; j < 16; j++) acc[i][j] = 0.f;

        for (int kt = 0; kt < NKT; kt++) {
            __syncthreads();   // buffer (kt&1) staged (vmcnt drained) & prev reads done
            if (kt < NKT - 1)      stage((kt + 1) & 1, (kt + 1) * KT, c0);
            else if (ch < NCH - 1) stage(0, 0, c0 + CT);   // next chunk's kt0
            const float* Ab = &sA[(kt & 1) * 512];
            const float* Bb = &sB[(kt & 1) * 4096];
            #pragma unroll
            for (int k = 0; k < KT; k++) {
                const float4 a0 = *(const float4*)&Ab[k * 64 + ty8];
                const float4 a1 = *(const float4*)&Ab[k * 64 + ty8 + 4];
                const float4 b0 = *(const float4*)&Bb[k * 512 + tx4];
                const float4 b1 = *(const float4*)&Bb[k * 512 + tx4 + 128];
                const float4 b2 = *(const float4*)&Bb[k * 512 + tx4 + 256];
                const float4 b3 = *(const float4*)&Bb[k * 512 + tx4 + 384];
                const float av[8] = {a0.x, a0.y, a0.z, a0.w, a1.x, a1.y, a1.z, a1.w};
                const float bv[16] = {b0.x, b0.y, b0.z, b0.w, b1.x, b1.y, b1.z, b1.w,
                                      b2.x, b2.y, b2.z, b2.w, b3.x, b3.y, b3.z, b3.w};
                #pragma unroll
                for (int i = 0; i < 8; i++)
                    #pragma unroll
                    for (int j = 0; j < 16; j++)
                        acc[i][j] += av[i] * bv[j];
            }
        }

        // ---- barrier-free epilogue: 4 parts of 128 cols, wave-private sCw ----
        const int slr = (ty & 1) * 8;   // slice-local row base of this thread
        #pragma unroll 1
        for (int p = 0; p < 4; p++) {
            #pragma unroll
            for (int i = 0; i < 8; i++)
                *(float4*)&sCw[(slr + i) * SCW + tx4] =
                    make_float4(acc[i][p * 4] * scale,     acc[i][p * 4 + 1] * scale,
                                acc[i][p * 4 + 2] * scale, acc[i][p * 4 + 3] * scale);
            // (same wave writes & reads sCw; compiler inserts lgkmcnt waits)
            // stats: row sr, cols q*4 + m*16 (+e)
            #pragma unroll 1
            for (int m = 0; m < 8; m++) {
                float4 v4 = *(const float4*)&sCw[sr * SCW + q * 4 + m * 16];
                const float vv[4] = {v4.x, v4.y, v4.z, v4.w};
                #pragma unroll
                for (int e = 0; e < 4; e++) {
                    float v = vv[e];
                    int c = c0 + p * 128 + q * 4 + m * 16 + e;
                    z_loc += expf(v);
                    bool ins = (v > tmin) || (v == tmin && c < tmincol);
                    if (ins) {
                        #pragma unroll
                        for (int k = 0; k < TOPK; k++)
                            if (k == tminslot) { tv[k] = v; tc16[k] = c; }
                        tmin = tv[0]; tmincol = tc16[0]; tminslot = 0;
                        #pragma unroll
                        for (int k = 1; k < TOPK; k++) {
                            bool worse = (tv[k] < tmin) || (tv[k] == tmin && tc16[k] > tmincol);
                            if (worse) { tmin = tv[k]; tmincol = tc16[k]; tminslot = k; }
                        }
                    }
                }
            }
            // dump E = exp(l) fp16, coalesced 16B/lane
            #pragma unroll 1
            for (int it = 0; it < 4; it++) {
                int flat = it * 512 + lane * 8;
                int r = flat >> 7, cc = flat & 127;
                float4 fa = *(const float4*)&sCw[r * SCW + cc];
                float4 fb = *(const float4*)&sCw[r * SCW + cc + 4];
                struct alignas(16) H8 { __half2 a, b, c, d; };
                H8 h8 = {__floats2half2_rn(expf(fa.x), expf(fa.y)),
                         __floats2half2_rn(expf(fa.z), expf(fa.w)),
                         __floats2half2_rn(expf(fb.x), expf(fb.y)),
                         __floats2half2_rn(expf(fb.z), expf(fb.w))};
                *(H8*)&lhalf[((size_t)(b * N_ + s0 + w * 16 + r)) * N_ + c0 + p * 128 + cc] = h8;
            }
        }
    }

    // ---- final merge (wave-internal; leader q==0 merges lanes 4r..4r+3) ----
    // scratch: zq in smem[0,256) (sA buf0), vb in smem[1024,5120) (sB buf0),
    // cb in wave-private sCw. All regions' last cross-wave use was kt<=62.
    float* zq = smem;
    float* vb = smem + 1024;
    int*   cbw = (int*)sCw;
    zq[tid] = z_loc;
    #pragma unroll
    for (int k = 0; k < TOPK; k++) {
        vb[tid * 16 + k] = tv[k];
        cbw[lane * 16 + k] = tc16[k];
    }
    if (q == 0) {
        float Z = zq[tid] + zq[tid + 1] + zq[tid + 2] + zq[tid + 3];
        float lz = logf(Z);
        const int grow = s0 + w * 16 + sr;
        rzbuf[b * N_ + grow] = 1.0f / Z;
        tmin = -1e30f; tminslot = 0; tmincol = 0x7fffffff;
        #pragma unroll
        for (int k = 0; k < TOPK; k++) { tv[k] = -1e30f; tc16[k] = 0x7fffffff; }
        for (int qq = 0; qq < 4; qq++) {
            #pragma unroll 1
            for (int k = 0; k < TOPK; k++) {
                float v = vb[(tid + qq) * 16 + k];
                int c = cbw[(lane + qq) * 16 + k];
                bool ins = (v > tmin) || (v == tmin && c < tmincol);
                if (ins) {
                    #pragma unroll
                    for (int k2 = 0; k2 < TOPK; k2++)
                        if (k2 == tminslot) { tv[k2] = v; tc16[k2] = c; }
                    tmin = tv[0]; tmincol = tc16[0]; tminslot = 0;
                    #pragma unroll
                    for (int k2 = 1; k2 < TOPK; k2++) {
                        bool worse = (tv[k2] < tmin) || (tv[k2] == tmin && tc16[k2] > tmincol);
                        if (worse) { tmin = tv[k2]; tmincol = tc16[k2]; tminslot = k2; }
                    }
                }
            }
        }
        unsigned used = 0;
        size_t rowbase = ((size_t)b * N_ + grow) * TOPK;
        for (int o = 0; o < TOPK; o++) {
            float bvv = -1e31f; int bcc = 0x7fffffff; int bk = 0;
            #pragma unroll
            for (int k = 0; k < TOPK; k++) {
                bool u = (used >> k) & 1u;
                bool better = !u && ((tv[k] > bvv) || (tv[k] == bvv && tc16[k] < bcc));
                if (better) { bvv = tv[k]; bcc = tc16[k]; bk = k; }
            }
            used |= 1u << bk;
            topv[rowbase + o] = bvv - lz;
            topc[rowbase + o] = bcc;
        }
    }
}

// ---------------------------------------------------------------------------
// colsum[b][t] = sum_s E[s][t] * (1/Z_s). Grid (4 colchunks, 8 ssegs, 16 b).
// ---------------------------------------------------------------------------
__global__ __launch_bounds__(256) void colsum2(
    const __half* __restrict__ lhalf, const float* __restrict__ rzbuf,
    float* __restrict__ colsum)
{
    const int b = blockIdx.z, s0 = blockIdx.y * 256, t0 = blockIdx.x * 512;
    __shared__ float srz[256];
    srz[threadIdx.x] = rzbuf[b * N_ + s0 + threadIdx.x];
    __syncthreads();
    const int t = t0 + threadIdx.x * 2;
    const __half2* p = (const __half2*)(lhalf + ((size_t)(b * N_ + s0)) * N_ + t);
    float ax = 0.f, ay = 0.f;
    #pragma unroll 8
    for (int s = 0; s < 256; s++) {
        float2 f = __half22float2(p[(size_t)s * (N_ / 2)]);
        float r = srz[s];
        ax += f.x * r; ay += f.y * r;
    }
    atomicAdd(&colsum[b * N_ + t], ax);
    atomicAdd(&colsum[b * N_ + t + 1], ay);
}

// ---------------------------------------------------------------------------
// Greedy match: per-row current-best + rescan on collision. 1 block/batch.
// ---------------------------------------------------------------------------
__global__ __launch_bounds__(256) void match2(
    const float* __restrict__ topv, const int* __restrict__ topc,
    int* __restrict__ mrow, int* __restrict__ mcol)
{
    const int b = blockIdx.x, tid = threadIdx.x;
    __shared__ float bv[N_];
    __shared__ int bc[N_];
    __shared__ int sup[16];
    __shared__ float rv[256];
    __shared__ int rr[256];

    for (int r = tid; r < N_; r += 256) {
        bv[r] = topv[((size_t)b * N_ + r) * TOPK];
        bc[r] = topc[((size_t)b * N_ + r) * TOPK];
    }
    __syncthreads();

    for (int it = 0; it < S_; it++) {
        float mv = -1e30f; int mr = 0x7fffffff;
        #pragma unroll
        for (int j = 0; j < 8; j++) {
            int r = tid + j * 256;
            float v = bv[r];
            if (v > mv) { mv = v; mr = r; }
        }
        rv[tid] = mv; rr[tid] = mr;
        __syncthreads();
        for (int off = 128; off; off >>= 1) {
            if (tid < off) {
                float v2 = rv[tid + off];
                if (v2 > rv[tid] || (v2 == rv[tid] && rr[tid + off] < rr[tid])) {
                    rv[tid] = v2; rr[tid] = rr[tid + off];
                }
            }
            __syncthreads();
        }
        if (tid == 0) {
            int R = rr[0]; int C = bc[R];
            mrow[b * S_ + it] = R; mcol[b * S_ + it] = C;
            sup[it] = C;
            bv[R] = -1e30f;
        }
        __syncthreads();
        const int C = sup[it];
        for (int r = tid; r < N_; r += 256) {
            if (bc[r] == C && bv[r] > -1e29f) {
                float nv = -1e30f; int nc = 0x7fffffff;
                const float* tvp = &topv[((size_t)b * N_ + r) * TOPK];
                const int* tcp = &topc[((size_t)b * N_ + r) * TOPK];
                for (int k = 0; k < TOPK; k++) {
                    int c2 = tcp[k];
                    bool bad = false;
                    for (int qq = 0; qq <= it; qq++) bad = bad || (sup[qq] == c2);
                    if (!bad) { nv = tvp[k]; nc = c2; break; }
                }
                bv[r] = nv; bc[r] = nc;
            }
        }
        __syncthreads();
    }
}

// ---------------------------------------------------------------------------
// Final: means, Kabsch (3x3 Jacobi SVD in fp64), R and t. One block per batch.
// ---------------------------------------------------------------------------
__global__ void finish_kernel(const float* __restrict__ src,
                              const float* __restrict__ tgt,
                              const float* __restrict__ colsum,
                              const int* __restrict__ mrow,
                              const int* __restrict__ mcol,
                              float* __restrict__ out)
{
    const int b = blockIdx.x;
    const int tid = threadIdx.x;
    __shared__ float red[256];
    __shared__ float res[6];

    float ls[3] = {0, 0, 0}, lc[3] = {0, 0, 0};
    for (int n = tid; n < N_; n += 256) {
        float cs = colsum[b * N_ + n];
        #pragma unroll
        for (int j = 0; j < 3; j++) {
            ls[j] += src[(size_t)(b * N_ + n) * 3 + j];
            lc[j] += tgt[(size_t)(b * N_ + n) * 3 + j] * cs;
        }
    }
    for (int j = 0; j < 6; j++) {
        red[tid] = (j < 3) ? ls[j] : lc[j - 3];
        __syncthreads();
        for (int off = 128; off; off >>= 1) {
            if (tid < off) red[tid] += red[tid + off];
            __syncthreads();
        }
        if (tid == 0) res[j] = red[0] / (float)N_;
        __syncthreads();
    }

    if (tid == 0) {
        double ps[S_][3], pt[S_][3];
        double ms[3] = {0, 0, 0}, mt[3] = {0, 0, 0};
        for (int s = 0; s < S_; s++) {
            int r = mrow[b * S_ + s], c = mcol[b * S_ + s];
            for (int j = 0; j < 3; j++) {
                ps[s][j] = (double)src[(size_t)(b * N_ + r) * 3 + j];
                pt[s][j] = (double)tgt[(size_t)(b * N_ + c) * 3 + j];
                ms[j] += ps[s][j]; mt[j] += pt[s][j];
            }
        }
        for (int j = 0; j < 3; j++) { ms[j] /= S_; mt[j] /= S_; }
        double H[3][3] = {{0,0,0},{0,0,0},{0,0,0}};
        for (int s = 0; s < S_; s++)
            for (int i = 0; i < 3; i++)
                for (int j = 0; j < 3; j++)
                    H[i][j] += (ps[s][i] - ms[i]) * (pt[s][j] - mt[j]);

        double A[3][3], Vv[3][3] = {{1,0,0},{0,1,0},{0,0,1}};
        for (int i = 0; i < 3; i++)
            for (int j = 0; j < 3; j++) {
                double acc = 0;
                for (int k = 0; k < 3; k++) acc += H[k][i] * H[k][j];
                A[i][j] = acc;
            }
        for (int sweep = 0; sweep < 30; sweep++) {
            double off = fabs(A[0][1]) + fabs(A[0][2]) + fabs(A[1][2]);
            if (off < 1e-30) break;
            for (int pair = 0; pair < 3; pair++) {
                int p = (pair == 2) ? 1 : 0;
                int q = (pair == 0) ? 1 : 2;
                double apq = A[p][q];
                if (fabs(apq) < 1e-300) continue;
                double theta = (A[q][q] - A[p][p]) / (2.0 * apq);
                double tt = ((theta >= 0) ? 1.0 : -1.0) / (fabs(theta) + sqrt(theta * theta + 1.0));
                double cc = 1.0 / sqrt(tt * tt + 1.0);
                double ssn = tt * cc;
                for (int k = 0; k < 3; k++) {
                    double akp = A[k][p], akq = A[k][q];
                    A[k][p] = cc * akp - ssn * akq;
                    A[k][q] = ssn * akp + cc * akq;
                }
                for (int k = 0; k < 3; k++) {
                    double apk = A[p][k], aqk = A[q][k];
                    A[p][k] = cc * apk - ssn * aqk;
                    A[q][k] = ssn * apk + cc * aqk;
                }
                for (int k = 0; k < 3; k++) {
                    double vkp = Vv[k][p], vkq = Vv[k][q];
                    Vv[k][p] = cc * vkp - ssn * vkq;
                    Vv[k][q] = ssn * vkp + cc * vkq;
                }
            }
        }
        double wv[3] = {A[0][0], A[1][1], A[2][2]};
        for (int a = 0; a < 2; a++)
            for (int b2 = a + 1; b2 < 3; b2++)
                if (wv[b2] > wv[a]) {
                    double tw = wv[a]; wv[a] = wv[b2]; wv[b2] = tw;
                    for (int k = 0; k < 3; k++) {
                        double tv_ = Vv[k][a]; Vv[k][a] = Vv[k][b2]; Vv[k][b2] = tv_;
                    }
                }
        double U[3][3];
        for (int k = 0; k < 3; k++) {
            double u[3], nrm = 0;
            for (int i = 0; i < 3; i++) {
                double acc = 0;
                for (int j = 0; j < 3; j++) acc += H[i][j] * Vv[j][k];
                u[i] = acc; nrm += acc * acc;
            }
            nrm = sqrt(nrm);
            if (nrm < 1e-300) nrm = 1e-300;
            for (int i = 0; i < 3; i++) U[i][k] = u[i] / nrm;
        }
        double r[3][3];
        for (int i = 0; i < 3; i++)
            for (int j = 0; j < 3; j++) {
                double acc = 0;
                for (int k = 0; k < 3; k++) acc += Vv[i][k] * U[j][k];
                r[i][j] = acc;
            }
        double det = r[0][0] * (r[1][1] * r[2][2] - r[1][2] * r[2][1])
                   - r[0][1] * (r[1][0] * r[2][2] - r[1][2] * r[2][0])
                   + r[0][2] * (r[1][0] * r[2][1] - r[1][1] * r[2][0]);
        if (det < 0.0) {
            for (int i = 0; i < 3; i++)
                for (int j = 0; j < 3; j++)
                    r[i][j] -= 2.0 * Vv[i][2] * U[j][2];
        }
        double smean[3] = {(double)res[0], (double)res[1], (double)res[2]};
        double cmean[3] = {(double)res[3], (double)res[4], (double)res[5]};
        for (int i = 0; i < 3; i++)
            for (int j = 0; j < 3; j++)
                out[b * 9 + i * 3 + j] = (float)r[i][j];
        for (int i = 0; i < 3; i++) {
            double acc = cmean[i];
            for (int j = 0; j < 3; j++) acc -= r[i][j] * smean[j];
            out[B_ * 9 + b * 3 + i] = (float)acc;
        }
    }
}

// ---------------------------------------------------------------------------
extern "C" void kernel_launch(void* const* d_in, const int* in_sizes, int n_in,
                              void* d_out, int out_size, void* d_ws, size_t ws_size,
                              hipStream_t stream)
{
    const float* srcE = (const float*)d_in[0];
    const float* tgtE = (const float*)d_in[1];
    const float* src  = (const float*)d_in[2];
    const float* tgt  = (const float*)d_in[3];
    float* out = (float*)d_out;
    char* ws = (char*)d_ws;

    const size_t szLH = (size_t)B_ * N_ * N_ * sizeof(__half);   // 128 MiB
    size_t off = szLH;
    float* rzbuf  = (float*)(ws + off); off += (size_t)B_ * N_ * sizeof(float);
    float* topv   = (float*)(ws + off); off += (size_t)B_ * N_ * TOPK * sizeof(float);
    int*   topc   = (int*)(ws + off);   off += (size_t)B_ * N_ * TOPK * sizeof(int);
    float* colsum = (float*)(ws + off); off += (size_t)B_ * N_ * sizeof(float);
    int*   mrow   = (int*)(ws + off);   off += 1024;
    int*   mcol   = (int*)(ws + off);
    __half* lhalf = (__half*)ws;

    hipMemsetAsync(colsum, 0, (size_t)B_ * N_ * sizeof(float), stream);

    gemm4<<<dim3(N_ / RT, B_), 256, 0, stream>>>(srcE, tgtE, rzbuf, topv, topc, lhalf);
    colsum2<<<dim3(N_ / 512, 8, B_), 256, 0, stream>>>(lhalf, rzbuf, colsum);
    match2<<<B_, 256, 0, stream>>>(topv, topc, mrow, mcol);
    finish_kernel<<<B_, 256, 0, stream>>>(src, tgt, colsum, mrow, mcol, out);
}

// Round 5
// 5123.555 us; speedup vs baseline: 2.9394x; 2.9394x over previous
//
#include <hip/hip_runtime.h>
#include <hip/hip_fp16.h>
#include <math.h>

constexpr int B_ = 16;
constexpr int D_ = 512;
constexpr int N_ = 2048;
constexpr int S_ = 15;
constexpr int TOPK = 16;

// GEMM tiling: block = 64 rows x 512-col chunks (4 chunks), K in 64 tiles of 8.
// Thread tile 8x16. 512 blocks = exactly 2 resident per CU.
constexpr int RT = 64;
constexpr int CT = 512;
constexpr int KT = 8;
constexpr int NCH = N_ / CT;    // 4
constexpr int NKT = D_ / KT;    // 64
constexpr int SCW = 132;        // per-wave slice row stride (128 + 4 pad)

// async global->LDS, 16 bytes per lane (dest = wave-uniform base + lane*16)
__device__ __forceinline__ void gl_lds16(const float* g, float* s) {
    __builtin_amdgcn_global_load_lds(
        (const __attribute__((address_space(1))) unsigned int*)g,
        (__attribute__((address_space(3))) unsigned int*)s,
        16, 0, 0);
}

// ---------------------------------------------------------------------------
// Fused fp32 GEMM: logits -> (E=exp(l) fp16 dump, per-row Z, per-row sorted
// top-16 adjusted by -log Z). Grid (32 rowblocks, 16 batches), 256 threads.
// Epilogue is barrier-free: wave w owns rows [w*16, w*16+16) via a private
// LDS slice buffer. NOTE: the part loop 'p' MUST be fully unrolled so all
// acc[][] indices are compile-time constants (runtime indices demote the
// accumulator array to scratch -> 90+ GB of spill traffic, R4 post-mortem).
// ---------------------------------------------------------------------------
__global__ __launch_bounds__(256, 2) void gemm5(
    const float* __restrict__ srcE, const float* __restrict__ tgtE,
    float* __restrict__ rzbuf,            // [B][N] 1/Z
    float* __restrict__ topv,             // [B][N][16] sorted desc, adjusted (l - logZ)
    int*   __restrict__ topc,             // [B][N][16]
    __half* __restrict__ lhalf)           // [B][N][N] E = exp(l)
{
    // layout (floats): sA [0,1024) 2x8x64 | sB [1024,9216) 2x8x512 | sC [9216,17664) 4x16x132
    __shared__ __align__(16) float smem[17664];   // 69.0 KB -> 2 blocks/CU
    float* sA = smem;
    float* sB = smem + 1024;
    float* sC = smem + 9216;

    const int tid = threadIdx.x;
    const int b  = blockIdx.y;
    const int s0 = blockIdx.x * RT;
    const int w    = tid >> 6, lane = tid & 63;
    const int ty   = tid >> 5, tx = tid & 31;     // GEMM: rows ty*8..+7, cols tx*4 + j*128
    const int ty8  = ty * 8,  tx4 = tx * 4;
    const int sr   = lane >> 2, q = lane & 3;     // stats: global row s0+w*16+sr, col strip q
    const float scale = 0.044194173824159216f;    // 1/sqrt(512)

    const float* gsrc = srcE + (size_t)b * D_ * N_;
    const float* gtgt = tgtE + (size_t)b * D_ * N_;
    float* sCw = &sC[w * 16 * SCW];               // wave-private 16x132 slice buffer

    float z_loc = 0.f;
    float tv[TOPK];
    int   tc16[TOPK];
    float tmin = -1e30f; int tminslot = 0, tmincol = 0x7fffffff;
    #pragma unroll
    for (int k = 0; k < TOPK; k++) { tv[k] = -1e30f; tc16[k] = 0x7fffffff; }

    // ---- async staging: A-tile 8x64 (2 wave-instrs), B-tile 8x512 (16) ----
    auto stage = [&](int bi, int k0, int c0) {
        if (w < 2) {  // A: instr w covers k-rows w*4..w*4+3
            int kr = w * 4 + (lane >> 4);
            gl_lds16(gsrc + (size_t)(k0 + kr) * N_ + s0 + (lane & 15) * 4,
                     &sA[bi * 512 + w * 256]);
        }
        #pragma unroll
        for (int i = 0; i < 4; i++) {  // B: 16 instrs, idx = w*4+i -> (krow, col-half)
            int idx = w * 4 + i;
            int kr = idx >> 1, h = idx & 1;
            gl_lds16(gtgt + (size_t)(k0 + kr) * N_ + c0 + h * 256 + lane * 4,
                     &sB[bi * 4096 + kr * 512 + h * 256]);
        }
    };

    stage(0, 0, 0);

    for (int ch = 0; ch < NCH; ch++) {
        const int c0 = ch * CT;
        float acc[8][16];
        #pragma unroll
        for (int i = 0; i < 8; i++)
            #pragma unroll
            for (int j = 0; j < 16; j++) acc[i][j] = 0.f;

        for (int kt = 0; kt < NKT; kt++) {
            __syncthreads();   // buffer (kt&1) staged (vmcnt drained) & prev reads done
            if (kt < NKT - 1)      stage((kt + 1) & 1, (kt + 1) * KT, c0);
            else if (ch < NCH - 1) stage(0, 0, c0 + CT);   // next chunk's kt0
            const float* Ab = &sA[(kt & 1) * 512];
            const float* Bb = &sB[(kt & 1) * 4096];
            #pragma unroll
            for (int k = 0; k < KT; k++) {
                const float4 a0 = *(const float4*)&Ab[k * 64 + ty8];
                const float4 a1 = *(const float4*)&Ab[k * 64 + ty8 + 4];
                const float4 b0 = *(const float4*)&Bb[k * 512 + tx4];
                const float4 b1 = *(const float4*)&Bb[k * 512 + tx4 + 128];
                const float4 b2 = *(const float4*)&Bb[k * 512 + tx4 + 256];
                const float4 b3 = *(const float4*)&Bb[k * 512 + tx4 + 384];
                const float av[8] = {a0.x, a0.y, a0.z, a0.w, a1.x, a1.y, a1.z, a1.w};
                const float bv[16] = {b0.x, b0.y, b0.z, b0.w, b1.x, b1.y, b1.z, b1.w,
                                      b2.x, b2.y, b2.z, b2.w, b3.x, b3.y, b3.z, b3.w};
                #pragma unroll
                for (int i = 0; i < 8; i++)
                    #pragma unroll
                    for (int j = 0; j < 16; j++)
                        acc[i][j] += av[i] * bv[j];
            }
        }

        // ---- barrier-free epilogue: 4 parts of 128 cols, wave-private sCw ----
        // p FULLY UNROLLED: acc indices must be compile-time constants.
        const int slr = (ty & 1) * 8;   // slice-local row base of this thread
        #pragma unroll
        for (int p = 0; p < 4; p++) {
            #pragma unroll
            for (int i = 0; i < 8; i++)
                *(float4*)&sCw[(slr + i) * SCW + tx4] =
                    make_float4(acc[i][p * 4] * scale,     acc[i][p * 4 + 1] * scale,
                                acc[i][p * 4 + 2] * scale, acc[i][p * 4 + 3] * scale);
            // stats: row sr, cols q*4 + m*16 (+e)
            #pragma unroll 1
            for (int m = 0; m < 8; m++) {
                float4 v4 = *(const float4*)&sCw[sr * SCW + q * 4 + m * 16];
                const float vv[4] = {v4.x, v4.y, v4.z, v4.w};
                #pragma unroll
                for (int e = 0; e < 4; e++) {
                    float v = vv[e];
                    int c = c0 + p * 128 + q * 4 + m * 16 + e;
                    z_loc += expf(v);
                    bool ins = (v > tmin) || (v == tmin && c < tmincol);
                    if (ins) {
                        #pragma unroll
                        for (int k = 0; k < TOPK; k++)
                            if (k == tminslot) { tv[k] = v; tc16[k] = c; }
                        tmin = tv[0]; tmincol = tc16[0]; tminslot = 0;
                        #pragma unroll
                        for (int k = 1; k < TOPK; k++) {
                            bool worse = (tv[k] < tmin) || (tv[k] == tmin && tc16[k] > tmincol);
                            if (worse) { tmin = tv[k]; tmincol = tc16[k]; tminslot = k; }
                        }
                    }
                }
            }
            // dump E = exp(l) fp16, coalesced 16B/lane
            #pragma unroll 1
            for (int it = 0; it < 4; it++) {
                int flat = it * 512 + lane * 8;
                int r = flat >> 7, cc = flat & 127;
                float4 fa = *(const float4*)&sCw[r * SCW + cc];
                float4 fb = *(const float4*)&sCw[r * SCW + cc + 4];
                struct alignas(16) H8 { __half2 a, b, c, d; };
                H8 h8 = {__floats2half2_rn(expf(fa.x), expf(fa.y)),
                         __floats2half2_rn(expf(fa.z), expf(fa.w)),
                         __floats2half2_rn(expf(fb.x), expf(fb.y)),
                         __floats2half2_rn(expf(fb.z), expf(fb.w))};
                *(H8*)&lhalf[((size_t)(b * N_ + s0 + w * 16 + r)) * N_ + c0 + p * 128 + cc] = h8;
            }
        }
    }

    // ---- final merge (wave-internal; leader q==0 merges lanes 4r..4r+3) ----
    // scratch: zq in smem[0,256) (sA buf0), vb in smem[1024,5120) (sB buf0),
    // cb in wave-private sCw. All regions' last cross-wave use was kt<=62.
    float* zq = smem;
    float* vb = smem + 1024;
    int*   cbw = (int*)sCw;
    zq[tid] = z_loc;
    #pragma unroll
    for (int k = 0; k < TOPK; k++) {
        vb[tid * 16 + k] = tv[k];
        cbw[lane * 16 + k] = tc16[k];
    }
    if (q == 0) {
        float Z = zq[tid] + zq[tid + 1] + zq[tid + 2] + zq[tid + 3];
        float lz = logf(Z);
        const int grow = s0 + w * 16 + sr;
        rzbuf[b * N_ + grow] = 1.0f / Z;
        tmin = -1e30f; tminslot = 0; tmincol = 0x7fffffff;
        #pragma unroll
        for (int k = 0; k < TOPK; k++) { tv[k] = -1e30f; tc16[k] = 0x7fffffff; }
        for (int qq = 0; qq < 4; qq++) {
            #pragma unroll 1
            for (int k = 0; k < TOPK; k++) {
                float v = vb[(tid + qq) * 16 + k];
                int c = cbw[(lane + qq) * 16 + k];
                bool ins = (v > tmin) || (v == tmin && c < tmincol);
                if (ins) {
                    #pragma unroll
                    for (int k2 = 0; k2 < TOPK; k2++)
                        if (k2 == tminslot) { tv[k2] = v; tc16[k2] = c; }
                    tmin = tv[0]; tmincol = tc16[0]; tminslot = 0;
                    #pragma unroll
                    for (int k2 = 1; k2 < TOPK; k2++) {
                        bool worse = (tv[k2] < tmin) || (tv[k2] == tmin && tc16[k2] > tmincol);
                        if (worse) { tmin = tv[k2]; tmincol = tc16[k2]; tminslot = k2; }
                    }
                }
            }
        }
        unsigned used = 0;
        size_t rowbase = ((size_t)b * N_ + grow) * TOPK;
        for (int o = 0; o < TOPK; o++) {
            float bvv = -1e31f; int bcc = 0x7fffffff; int bk = 0;
            #pragma unroll
            for (int k = 0; k < TOPK; k++) {
                bool u = (used >> k) & 1u;
                bool better = !u && ((tv[k] > bvv) || (tv[k] == bvv && tc16[k] < bcc));
                if (better) { bvv = tv[k]; bcc = tc16[k]; bk = k; }
            }
            used |= 1u << bk;
            topv[rowbase + o] = bvv - lz;
            topc[rowbase + o] = bcc;
        }
    }
}

// ---------------------------------------------------------------------------
// colsum[b][t] = sum_s E[s][t] * (1/Z_s). Grid (4 colchunks, 8 ssegs, 16 b).
// ---------------------------------------------------------------------------
__global__ __launch_bounds__(256) void colsum2(
    const __half* __restrict__ lhalf, const float* __restrict__ rzbuf,
    float* __restrict__ colsum)
{
    const int b = blockIdx.z, s0 = blockIdx.y * 256, t0 = blockIdx.x * 512;
    __shared__ float srz[256];
    srz[threadIdx.x] = rzbuf[b * N_ + s0 + threadIdx.x];
    __syncthreads();
    const int t = t0 + threadIdx.x * 2;
    const __half2* p = (const __half2*)(lhalf + ((size_t)(b * N_ + s0)) * N_ + t);
    float ax = 0.f, ay = 0.f;
    #pragma unroll 8
    for (int s = 0; s < 256; s++) {
        float2 f = __half22float2(p[(size_t)s * (N_ / 2)]);
        float r = srz[s];
        ax += f.x * r; ay += f.y * r;
    }
    atomicAdd(&colsum[b * N_ + t], ax);
    atomicAdd(&colsum[b * N_ + t + 1], ay);
}

// ---------------------------------------------------------------------------
// Greedy match: per-row current-best + rescan on collision. 1 block/batch.
// ---------------------------------------------------------------------------
__global__ __launch_bounds__(256) void match2(
    const float* __restrict__ topv, const int* __restrict__ topc,
    int* __restrict__ mrow, int* __restrict__ mcol)
{
    const int b = blockIdx.x, tid = threadIdx.x;
    __shared__ float bv[N_];
    __shared__ int bc[N_];
    __shared__ int sup[16];
    __shared__ float rv[256];
    __shared__ int rr[256];

    for (int r = tid; r < N_; r += 256) {
        bv[r] = topv[((size_t)b * N_ + r) * TOPK];
        bc[r] = topc[((size_t)b * N_ + r) * TOPK];
    }
    __syncthreads();

    for (int it = 0; it < S_; it++) {
        float mv = -1e30f; int mr = 0x7fffffff;
        #pragma unroll
        for (int j = 0; j < 8; j++) {
            int r = tid + j * 256;
            float v = bv[r];
            if (v > mv) { mv = v; mr = r; }
        }
        rv[tid] = mv; rr[tid] = mr;
        __syncthreads();
        for (int off = 128; off; off >>= 1) {
            if (tid < off) {
                float v2 = rv[tid + off];
                if (v2 > rv[tid] || (v2 == rv[tid] && rr[tid + off] < rr[tid])) {
                    rv[tid] = v2; rr[tid] = rr[tid + off];
                }
            }
            __syncthreads();
        }
        if (tid == 0) {
            int R = rr[0]; int C = bc[R];
            mrow[b * S_ + it] = R; mcol[b * S_ + it] = C;
            sup[it] = C;
            bv[R] = -1e30f;
        }
        __syncthreads();
        const int C = sup[it];
        for (int r = tid; r < N_; r += 256) {
            if (bc[r] == C && bv[r] > -1e29f) {
                float nv = -1e30f; int nc = 0x7fffffff;
                const float* tvp = &topv[((size_t)b * N_ + r) * TOPK];
                const int* tcp = &topc[((size_t)b * N_ + r) * TOPK];
                for (int k = 0; k < TOPK; k++) {
                    int c2 = tcp[k];
                    bool bad = false;
                    for (int qq = 0; qq <= it; qq++) bad = bad || (sup[qq] == c2);
                    if (!bad) { nv = tvp[k]; nc = c2; break; }
                }
                bv[r] = nv; bc[r] = nc;
            }
        }
        __syncthreads();
    }
}

// ---------------------------------------------------------------------------
// Final: means, Kabsch (3x3 Jacobi SVD in fp64), R and t. One block per batch.
// ---------------------------------------------------------------------------
__global__ void finish_kernel(const float* __restrict__ src,
                              const float* __restrict__ tgt,
                              const float* __restrict__ colsum,
                              const int* __restrict__ mrow,
                              const int* __restrict__ mcol,
                              float* __restrict__ out)
{
    const int b = blockIdx.x;
    const int tid = threadIdx.x;
    __shared__ float red[256];
    __shared__ float res[6];

    float ls[3] = {0, 0, 0}, lc[3] = {0, 0, 0};
    for (int n = tid; n < N_; n += 256) {
        float cs = colsum[b * N_ + n];
        #pragma unroll
        for (int j = 0; j < 3; j++) {
            ls[j] += src[(size_t)(b * N_ + n) * 3 + j];
            lc[j] += tgt[(size_t)(b * N_ + n) * 3 + j] * cs;
        }
    }
    for (int j = 0; j < 6; j++) {
        red[tid] = (j < 3) ? ls[j] : lc[j - 3];
        __syncthreads();
        for (int off = 128; off; off >>= 1) {
            if (tid < off) red[tid] += red[tid + off];
            __syncthreads();
        }
        if (tid == 0) res[j] = red[0] / (float)N_;
        __syncthreads();
    }

    if (tid == 0) {
        double ps[S_][3], pt[S_][3];
        double ms[3] = {0, 0, 0}, mt[3] = {0, 0, 0};
        for (int s = 0; s < S_; s++) {
            int r = mrow[b * S_ + s], c = mcol[b * S_ + s];
            for (int j = 0; j < 3; j++) {
                ps[s][j] = (double)src[(size_t)(b * N_ + r) * 3 + j];
                pt[s][j] = (double)tgt[(size_t)(b * N_ + c) * 3 + j];
                ms[j] += ps[s][j]; mt[j] += pt[s][j];
            }
        }
        for (int j = 0; j < 3; j++) { ms[j] /= S_; mt[j] /= S_; }
        double H[3][3] = {{0,0,0},{0,0,0},{0,0,0}};
        for (int s = 0; s < S_; s++)
            for (int i = 0; i < 3; i++)
                for (int j = 0; j < 3; j++)
                    H[i][j] += (ps[s][i] - ms[i]) * (pt[s][j] - mt[j]);

        double A[3][3], Vv[3][3] = {{1,0,0},{0,1,0},{0,0,1}};
        for (int i = 0; i < 3; i++)
            for (int j = 0; j < 3; j++) {
                double acc = 0;
                for (int k = 0; k < 3; k++) acc += H[k][i] * H[k][j];
                A[i][j] = acc;
            }
        for (int sweep = 0; sweep < 30; sweep++) {
            double off = fabs(A[0][1]) + fabs(A[0][2]) + fabs(A[1][2]);
            if (off < 1e-30) break;
            for (int pair = 0; pair < 3; pair++) {
                int p = (pair == 2) ? 1 : 0;
                int q = (pair == 0) ? 1 : 2;
                double apq = A[p][q];
                if (fabs(apq) < 1e-300) continue;
                double theta = (A[q][q] - A[p][p]) / (2.0 * apq);
                double tt = ((theta >= 0) ? 1.0 : -1.0) / (fabs(theta) + sqrt(theta * theta + 1.0));
                double cc = 1.0 / sqrt(tt * tt + 1.0);
                double ssn = tt * cc;
                for (int k = 0; k < 3; k++) {
                    double akp = A[k][p], akq = A[k][q];
                    A[k][p] = cc * akp - ssn * akq;
                    A[k][q] = ssn * akp + cc * akq;
                }
                for (int k = 0; k < 3; k++) {
                    double apk = A[p][k], aqk = A[q][k];
                    A[p][k] = cc * apk - ssn * aqk;
                    A[q][k] = ssn * apk + cc * aqk;
                }
                for (int k = 0; k < 3; k++) {
                    double vkp = Vv[k][p], vkq = Vv[k][q];
                    Vv[k][p] = cc * vkp - ssn * vkq;
                    Vv[k][q] = ssn * vkp + cc * vkq;
                }
            }
        }
        double wv[3] = {A[0][0], A[1][1], A[2][2]};
        for (int a = 0; a < 2; a++)
            for (int b2 = a + 1; b2 < 3; b2++)
                if (wv[b2] > wv[a]) {
                    double tw = wv[a]; wv[a] = wv[b2]; wv[b2] = tw;
                    for (int k = 0; k < 3; k++) {
                        double tv_ = Vv[k][a]; Vv[k][a] = Vv[k][b2]; Vv[k][b2] = tv_;
                    }
                }
        double U[3][3];
        for (int k = 0; k < 3; k++) {
            double u[3], nrm = 0;
            for (int i = 0; i < 3; i++) {
                double acc = 0;
                for (int j = 0; j < 3; j++) acc += H[i][j] * Vv[j][k];
                u[i] = acc; nrm += acc * acc;
            }
            nrm = sqrt(nrm);
            if (nrm < 1e-300) nrm = 1e-300;
            for (int i = 0; i < 3; i++) U[i][k] = u[i] / nrm;
        }
        double r[3][3];
        for (int i = 0; i < 3; i++)
            for (int j = 0; j < 3; j++) {
                double acc = 0;
                for (int k = 0; k < 3; k++) acc += Vv[i][k] * U[j][k];
                r[i][j] = acc;
            }
        double det = r[0][0] * (r[1][1] * r[2][2] - r[1][2] * r[2][1])
                   - r[0][1] * (r[1][0] * r[2][2] - r[1][2] * r[2][0])
                   + r[0][2] * (r[1][0] * r[2][1] - r[1][1] * r[2][0]);
        if (det < 0.0) {
            for (int i = 0; i < 3; i++)
                for (int j = 0; j < 3; j++)
                    r[i][j] -= 2.0 * Vv[i][2] * U[j][2];
        }
        double smean[3] = {(double)res[0], (double)res[1], (double)res[2]};
        double cmean[3] = {(double)res[3], (double)res[4], (double)res[5]};
        for (int i = 0; i < 3; i++)
            for (int j = 0; j < 3; j++)
                out[b * 9 + i * 3 + j] = (float)r[i][j];
        for (int i = 0; i < 3; i++) {
            double acc = cmean[i];
            for (int j = 0; j < 3; j++) acc -= r[i][j] * smean[j];
            out[B_ * 9 + b * 3 + i] = (float)acc;
        }
    }
}

// ---------------------------------------------------------------------------
extern "C" void kernel_launch(void* const* d_in, const int* in_sizes, int n_in,
                              void* d_out, int out_size, void* d_ws, size_t ws_size,
                              hipStream_t stream)
{
    const float* srcE = (const float*)d_in[0];
    const float* tgtE = (const float*)d_in[1];
    const float* src  = (const float*)d_in[2];
    const float* tgt  = (const float*)d_in[3];
    float* out = (float*)d_out;
    char* ws = (char*)d_ws;

    const size_t szLH = (size_t)B_ * N_ * N_ * sizeof(__half);   // 128 MiB
    size_t off = szLH;
    float* rzbuf  = (float*)(ws + off); off += (size_t)B_ * N_ * sizeof(float);
    float* topv   = (float*)(ws + off); off += (size_t)B_ * N_ * TOPK * sizeof(float);
    int*   topc   = (int*)(ws + off);   off += (size_t)B_ * N_ * TOPK * sizeof(int);
    float* colsum = (float*)(ws + off); off += (size_t)B_ * N_ * sizeof(float);
    int*   mrow   = (int*)(ws + off);   off += 1024;
    int*   mcol   = (int*)(ws + off);
    __half* lhalf = (__half*)ws;

    hipMemsetAsync(colsum, 0, (size_t)B_ * N_ * sizeof(float), stream);

    gemm5<<<dim3(N_ / RT, B_), 256, 0, stream>>>(srcE, tgtE, rzbuf, topv, topc, lhalf);
    colsum2<<<dim3(N_ / 512, 8, B_), 256, 0, stream>>>(lhalf, rzbuf, colsum);
    match2<<<B_, 256, 0, stream>>>(topv, topc, mrow, mcol);
    finish_kernel<<<B_, 256, 0, stream>>>(src, tgt, colsum, mrow, mcol, out);
}

// Round 6
// 1678.282 us; speedup vs baseline: 8.9734x; 3.0529x over previous
//
#include <hip/hip_runtime.h>
#include <hip/hip_fp16.h>
#include <math.h>

constexpr int B_ = 16;
constexpr int D_ = 512;
constexpr int N_ = 2048;
constexpr int S_ = 15;
constexpr int TOPK = 16;

// GEMM tiling: block = 64 rows x 256-col chunks (8 chunks), K in 64 tiles of 8.
// Thread tile 8x8 -> 64 acc regs: fits the observed 128-VGPR budget (R5
// post-mortem: 8x16 = 128 acc spilled ~80 regs to scratch -> 17 GB traffic).
constexpr int RT = 64;
constexpr int CT = 256;
constexpr int KT = 8;
constexpr int NCH = N_ / CT;    // 8
constexpr int NKT = D_ / KT;    // 64
constexpr int SCW = 132;        // per-wave slice row stride (128 + 4 pad)

// async global->LDS, 16 bytes per lane (dest = wave-uniform base + lane*16)
__device__ __forceinline__ void gl_lds16(const float* g, float* s) {
    __builtin_amdgcn_global_load_lds(
        (const __attribute__((address_space(1))) unsigned int*)g,
        (__attribute__((address_space(3))) unsigned int*)s,
        16, 0, 0);
}

// ---------------------------------------------------------------------------
// Fused fp32 GEMM: logits -> (E=exp(l) fp16 dump, per-row Z, per-row sorted
// top-16 adjusted by -log Z). Grid (32 rowblocks, 16 batches), 256 threads.
// Epilogue is barrier-free: wave w owns rows [w*16, w*16+16) via a private
// LDS slice buffer, processed in two 128-col parts per chunk. All acc[][]
// indices are compile-time constants (dynamic index -> scratch demotion).
// ---------------------------------------------------------------------------
__global__ __launch_bounds__(256, 2) void gemm6(
    const float* __restrict__ srcE, const float* __restrict__ tgtE,
    float* __restrict__ rzbuf,            // [B][N] 1/Z
    float* __restrict__ topv,             // [B][N][16] sorted desc, adjusted (l - logZ)
    int*   __restrict__ topc,             // [B][N][16]
    __half* __restrict__ lhalf)           // [B][N][N] E = exp(l)
{
    // layout (floats): sA [0,1024) 2x8x64 | sB [1024,5120) 2x8x256
    //                  sC [5120,13568) 4 waves x 16x132
    __shared__ __align__(16) float smem[13568];   // 53 KB
    float* sA = smem;
    float* sB = smem + 1024;
    float* sC = smem + 5120;

    const int tid = threadIdx.x;
    const int b  = blockIdx.y;
    const int s0 = blockIdx.x * RT;
    const int w    = tid >> 6, lane = tid & 63;
    const int ty   = tid >> 5, tx = tid & 31;     // GEMM: rows ty*8..+7, cols tx*4 / 128+tx*4
    const int ty8  = ty * 8,  tx4 = tx * 4;
    const int sr   = lane >> 2, q = lane & 3;     // stats: slice row sr, col strip q
    const float scale = 0.044194173824159216f;    // 1/sqrt(512)

    const float* gsrc = srcE + (size_t)b * D_ * N_;
    const float* gtgt = tgtE + (size_t)b * D_ * N_;
    float* sCw = &sC[w * 16 * SCW];               // wave-private 16x132 slice buffer

    float z_loc = 0.f;
    float tv[TOPK];
    int   tc16[TOPK];
    float tmin = -1e30f; int tminslot = 0, tmincol = 0x7fffffff;
    #pragma unroll
    for (int k = 0; k < TOPK; k++) { tv[k] = -1e30f; tc16[k] = 0x7fffffff; }

    // ---- async staging: A-tile 8x64 (2 wave-instrs), B-tile 8x256 (8) ----
    auto stage = [&](int bi, int k0, int c0) {
        if (w < 2) {  // A: instr w covers k-rows w*4..w*4+3
            int kr = w * 4 + (lane >> 4);
            gl_lds16(gsrc + (size_t)(k0 + kr) * N_ + s0 + (lane & 15) * 4,
                     &sA[bi * 512 + w * 256]);
        }
        #pragma unroll
        for (int i = 0; i < 2; i++) {  // B: 8 instrs, one k-row (1 KB) each
            int kr = w * 2 + i;
            gl_lds16(gtgt + (size_t)(k0 + kr) * N_ + c0 + lane * 4,
                     &sB[bi * 2048 + kr * 256]);
        }
    };

    stage(0, 0, 0);

    for (int ch = 0; ch < NCH; ch++) {
        const int c0 = ch * CT;
        float acc[8][8];
        #pragma unroll
        for (int i = 0; i < 8; i++)
            #pragma unroll
            for (int j = 0; j < 8; j++) acc[i][j] = 0.f;

        for (int kt = 0; kt < NKT; kt++) {
            __syncthreads();   // buffer (kt&1) staged (vmcnt drained) & prev reads done
            if (kt < NKT - 1)      stage((kt + 1) & 1, (kt + 1) * KT, c0);
            else if (ch < NCH - 1) stage(0, 0, c0 + CT);   // next chunk's kt0
            const float* Ab = &sA[(kt & 1) * 512];
            const float* Bb = &sB[(kt & 1) * 2048];
            #pragma unroll
            for (int k = 0; k < KT; k++) {
                const float4 a0 = *(const float4*)&Ab[k * 64 + ty8];
                const float4 a1 = *(const float4*)&Ab[k * 64 + ty8 + 4];
                const float4 b0 = *(const float4*)&Bb[k * 256 + tx4];
                const float4 b1 = *(const float4*)&Bb[k * 256 + 128 + tx4];
                const float av[8] = {a0.x, a0.y, a0.z, a0.w, a1.x, a1.y, a1.z, a1.w};
                const float bv[8] = {b0.x, b0.y, b0.z, b0.w, b1.x, b1.y, b1.z, b1.w};
                #pragma unroll
                for (int i = 0; i < 8; i++)
                    #pragma unroll
                    for (int j = 0; j < 8; j++)
                        acc[i][j] += av[i] * bv[j];
            }
        }

        // ---- barrier-free epilogue: 2 parts of 128 cols, wave-private sCw ----
        const int slr = (ty & 1) * 8;   // slice-local row base of this thread
        #pragma unroll
        for (int p = 0; p < 2; p++) {
            #pragma unroll
            for (int i = 0; i < 8; i++)
                *(float4*)&sCw[(slr + i) * SCW + tx4] =
                    make_float4(acc[i][p * 4] * scale,     acc[i][p * 4 + 1] * scale,
                                acc[i][p * 4 + 2] * scale, acc[i][p * 4 + 3] * scale);
            // stats: slice row sr, cols q*4 + m*16 (+e)
            #pragma unroll 1
            for (int m = 0; m < 8; m++) {
                float4 v4 = *(const float4*)&sCw[sr * SCW + q * 4 + m * 16];
                const float vv[4] = {v4.x, v4.y, v4.z, v4.w};
                #pragma unroll
                for (int e = 0; e < 4; e++) {
                    float v = vv[e];
                    int c = c0 + p * 128 + q * 4 + m * 16 + e;
                    z_loc += expf(v);
                    bool ins = (v > tmin) || (v == tmin && c < tmincol);
                    if (ins) {
                        #pragma unroll
                        for (int k = 0; k < TOPK; k++)
                            if (k == tminslot) { tv[k] = v; tc16[k] = c; }
                        tmin = tv[0]; tmincol = tc16[0]; tminslot = 0;
                        #pragma unroll
                        for (int k = 1; k < TOPK; k++) {
                            bool worse = (tv[k] < tmin) || (tv[k] == tmin && tc16[k] > tmincol);
                            if (worse) { tmin = tv[k]; tmincol = tc16[k]; tminslot = k; }
                        }
                    }
                }
            }
            // dump E = exp(l) fp16, coalesced 16B/lane
            #pragma unroll 1
            for (int it = 0; it < 4; it++) {
                int flat = it * 512 + lane * 8;
                int r = flat >> 7, cc = flat & 127;
                float4 fa = *(const float4*)&sCw[r * SCW + cc];
                float4 fb = *(const float4*)&sCw[r * SCW + cc + 4];
                struct alignas(16) H8 { __half2 a, b, c, d; };
                H8 h8 = {__floats2half2_rn(expf(fa.x), expf(fa.y)),
                         __floats2half2_rn(expf(fa.z), expf(fa.w)),
                         __floats2half2_rn(expf(fb.x), expf(fb.y)),
                         __floats2half2_rn(expf(fb.z), expf(fb.w))};
                *(H8*)&lhalf[((size_t)(b * N_ + s0 + w * 16 + r)) * N_ + c0 + p * 128 + cc] = h8;
            }
        }
    }

    // ---- final merge: entirely wave-private (inside own sCw slice, 2112 f):
    //   cbw ints [0,1024) | vbw floats [1024,2048) | zqw floats [2048,2112)
    // Leader lane q==0 merges lanes 4*sr..4*sr+3 (same wave, lockstep; no
    // cross-wave region reuse -> no barrier needed).
    int*   cbw = (int*)sCw;
    float* vbw = sCw + 1024;
    float* zqw = sCw + 2048;
    zqw[lane] = z_loc;
    #pragma unroll
    for (int k = 0; k < TOPK; k++) {
        vbw[lane * 16 + k] = tv[k];
        cbw[lane * 16 + k] = tc16[k];
    }
    if (q == 0) {
        float Z = zqw[lane] + zqw[lane + 1] + zqw[lane + 2] + zqw[lane + 3];
        float lz = logf(Z);
        const int grow = s0 + w * 16 + sr;
        rzbuf[b * N_ + grow] = 1.0f / Z;
        tmin = -1e30f; tminslot = 0; tmincol = 0x7fffffff;
        #pragma unroll
        for (int k = 0; k < TOPK; k++) { tv[k] = -1e30f; tc16[k] = 0x7fffffff; }
        for (int qq = 0; qq < 4; qq++) {
            #pragma unroll 1
            for (int k = 0; k < TOPK; k++) {
                float v = vbw[(lane + qq) * 16 + k];
                int c = cbw[(lane + qq) * 16 + k];
                bool ins = (v > tmin) || (v == tmin && c < tmincol);
                if (ins) {
                    #pragma unroll
                    for (int k2 = 0; k2 < TOPK; k2++)
                        if (k2 == tminslot) { tv[k2] = v; tc16[k2] = c; }
                    tmin = tv[0]; tmincol = tc16[0]; tminslot = 0;
                    #pragma unroll
                    for (int k2 = 1; k2 < TOPK; k2++) {
                        bool worse = (tv[k2] < tmin) || (tv[k2] == tmin && tc16[k2] > tmincol);
                        if (worse) { tmin = tv[k2]; tmincol = tc16[k2]; tminslot = k2; }
                    }
                }
            }
        }
        unsigned used = 0;
        size_t rowbase = ((size_t)b * N_ + grow) * TOPK;
        for (int o = 0; o < TOPK; o++) {
            float bvv = -1e31f; int bcc = 0x7fffffff; int bk = 0;
            #pragma unroll
            for (int k = 0; k < TOPK; k++) {
                bool u = (used >> k) & 1u;
                bool better = !u && ((tv[k] > bvv) || (tv[k] == bvv && tc16[k] < bcc));
                if (better) { bvv = tv[k]; bcc = tc16[k]; bk = k; }
            }
            used |= 1u << bk;
            topv[rowbase + o] = bvv - lz;
            topc[rowbase + o] = bcc;
        }
    }
}

// ---------------------------------------------------------------------------
// colsum[b][t] = sum_s E[s][t] * (1/Z_s). Grid (4 colchunks, 8 ssegs, 16 b).
// ---------------------------------------------------------------------------
__global__ __launch_bounds__(256) void colsum2(
    const __half* __restrict__ lhalf, const float* __restrict__ rzbuf,
    float* __restrict__ colsum)
{
    const int b = blockIdx.z, s0 = blockIdx.y * 256, t0 = blockIdx.x * 512;
    __shared__ float srz[256];
    srz[threadIdx.x] = rzbuf[b * N_ + s0 + threadIdx.x];
    __syncthreads();
    const int t = t0 + threadIdx.x * 2;
    const __half2* p = (const __half2*)(lhalf + ((size_t)(b * N_ + s0)) * N_ + t);
    float ax = 0.f, ay = 0.f;
    #pragma unroll 8
    for (int s = 0; s < 256; s++) {
        float2 f = __half22float2(p[(size_t)s * (N_ / 2)]);
        float r = srz[s];
        ax += f.x * r; ay += f.y * r;
    }
    atomicAdd(&colsum[b * N_ + t], ax);
    atomicAdd(&colsum[b * N_ + t + 1], ay);
}

// ---------------------------------------------------------------------------
// Greedy match: per-row current-best + rescan on collision. 1 block/batch.
// ---------------------------------------------------------------------------
__global__ __launch_bounds__(256) void match2(
    const float* __restrict__ topv, const int* __restrict__ topc,
    int* __restrict__ mrow, int* __restrict__ mcol)
{
    const int b = blockIdx.x, tid = threadIdx.x;
    __shared__ float bv[N_];
    __shared__ int bc[N_];
    __shared__ int sup[16];
    __shared__ float rv[256];
    __shared__ int rr[256];

    for (int r = tid; r < N_; r += 256) {
        bv[r] = topv[((size_t)b * N_ + r) * TOPK];
        bc[r] = topc[((size_t)b * N_ + r) * TOPK];
    }
    __syncthreads();

    for (int it = 0; it < S_; it++) {
        float mv = -1e30f; int mr = 0x7fffffff;
        #pragma unroll
        for (int j = 0; j < 8; j++) {
            int r = tid + j * 256;
            float v = bv[r];
            if (v > mv) { mv = v; mr = r; }
        }
        rv[tid] = mv; rr[tid] = mr;
        __syncthreads();
        for (int off = 128; off; off >>= 1) {
            if (tid < off) {
                float v2 = rv[tid + off];
                if (v2 > rv[tid] || (v2 == rv[tid] && rr[tid + off] < rr[tid])) {
                    rv[tid] = v2; rr[tid] = rr[tid + off];
                }
            }
            __syncthreads();
        }
        if (tid == 0) {
            int R = rr[0]; int C = bc[R];
            mrow[b * S_ + it] = R; mcol[b * S_ + it] = C;
            sup[it] = C;
            bv[R] = -1e30f;
        }
        __syncthreads();
        const int C = sup[it];
        for (int r = tid; r < N_; r += 256) {
            if (bc[r] == C && bv[r] > -1e29f) {
                float nv = -1e30f; int nc = 0x7fffffff;
                const float* tvp = &topv[((size_t)b * N_ + r) * TOPK];
                const int* tcp = &topc[((size_t)b * N_ + r) * TOPK];
                for (int k = 0; k < TOPK; k++) {
                    int c2 = tcp[k];
                    bool bad = false;
                    for (int qq = 0; qq <= it; qq++) bad = bad || (sup[qq] == c2);
                    if (!bad) { nv = tvp[k]; nc = c2; break; }
                }
                bv[r] = nv; bc[r] = nc;
            }
        }
        __syncthreads();
    }
}

// ---------------------------------------------------------------------------
// Final: means, Kabsch (3x3 Jacobi SVD in fp64), R and t. One block per batch.
// ---------------------------------------------------------------------------
__global__ void finish_kernel(const float* __restrict__ src,
                              const float* __restrict__ tgt,
                              const float* __restrict__ colsum,
                              const int* __restrict__ mrow,
                              const int* __restrict__ mcol,
                              float* __restrict__ out)
{
    const int b = blockIdx.x;
    const int tid = threadIdx.x;
    __shared__ float red[256];
    __shared__ float res[6];

    float ls[3] = {0, 0, 0}, lc[3] = {0, 0, 0};
    for (int n = tid; n < N_; n += 256) {
        float cs = colsum[b * N_ + n];
        #pragma unroll
        for (int j = 0; j < 3; j++) {
            ls[j] += src[(size_t)(b * N_ + n) * 3 + j];
            lc[j] += tgt[(size_t)(b * N_ + n) * 3 + j] * cs;
        }
    }
    for (int j = 0; j < 6; j++) {
        red[tid] = (j < 3) ? ls[j] : lc[j - 3];
        __syncthreads();
        for (int off = 128; off; off >>= 1) {
            if (tid < off) red[tid] += red[tid + off];
            __syncthreads();
        }
        if (tid == 0) res[j] = red[0] / (float)N_;
        __syncthreads();
    }

    if (tid == 0) {
        double ps[S_][3], pt[S_][3];
        double ms[3] = {0, 0, 0}, mt[3] = {0, 0, 0};
        for (int s = 0; s < S_; s++) {
            int r = mrow[b * S_ + s], c = mcol[b * S_ + s];
            for (int j = 0; j < 3; j++) {
                ps[s][j] = (double)src[(size_t)(b * N_ + r) * 3 + j];
                pt[s][j] = (double)tgt[(size_t)(b * N_ + c) * 3 + j];
                ms[j] += ps[s][j]; mt[j] += pt[s][j];
            }
        }
        for (int j = 0; j < 3; j++) { ms[j] /= S_; mt[j] /= S_; }
        double H[3][3] = {{0,0,0},{0,0,0},{0,0,0}};
        for (int s = 0; s < S_; s++)
            for (int i = 0; i < 3; i++)
                for (int j = 0; j < 3; j++)
                    H[i][j] += (ps[s][i] - ms[i]) * (pt[s][j] - mt[j]);

        double A[3][3], Vv[3][3] = {{1,0,0},{0,1,0},{0,0,1}};
        for (int i = 0; i < 3; i++)
            for (int j = 0; j < 3; j++) {
                double acc = 0;
                for (int k = 0; k < 3; k++) acc += H[k][i] * H[k][j];
                A[i][j] = acc;
            }
        for (int sweep = 0; sweep < 30; sweep++) {
            double off = fabs(A[0][1]) + fabs(A[0][2]) + fabs(A[1][2]);
            if (off < 1e-30) break;
            for (int pair = 0; pair < 3; pair++) {
                int p = (pair == 2) ? 1 : 0;
                int q = (pair == 0) ? 1 : 2;
                double apq = A[p][q];
                if (fabs(apq) < 1e-300) continue;
                double theta = (A[q][q] - A[p][p]) / (2.0 * apq);
                double tt = ((theta >= 0) ? 1.0 : -1.0) / (fabs(theta) + sqrt(theta * theta + 1.0));
                double cc = 1.0 / sqrt(tt * tt + 1.0);
                double ssn = tt * cc;
                for (int k = 0; k < 3; k++) {
                    double akp = A[k][p], akq = A[k][q];
                    A[k][p] = cc * akp - ssn * akq;
                    A[k][q] = ssn * akp + cc * akq;
                }
                for (int k = 0; k < 3; k++) {
                    double apk = A[p][k], aqk = A[q][k];
                    A[p][k] = cc * apk - ssn * aqk;
                    A[q][k] = ssn * apk + cc * aqk;
                }
                for (int k = 0; k < 3; k++) {
                    double vkp = Vv[k][p], vkq = Vv[k][q];
                    Vv[k][p] = cc * vkp - ssn * vkq;
                    Vv[k][q] = ssn * vkp + cc * vkq;
                }
            }
        }
        double wv[3] = {A[0][0], A[1][1], A[2][2]};
        for (int a = 0; a < 2; a++)
            for (int b2 = a + 1; b2 < 3; b2++)
                if (wv[b2] > wv[a]) {
                    double tw = wv[a]; wv[a] = wv[b2]; wv[b2] = tw;
                    for (int k = 0; k < 3; k++) {
                        double tv_ = Vv[k][a]; Vv[k][a] = Vv[k][b2]; Vv[k][b2] = tv_;
                    }
                }
        double U[3][3];
        for (int k = 0; k < 3; k++) {
            double u[3], nrm = 0;
            for (int i = 0; i < 3; i++) {
                double acc = 0;
                for (int j = 0; j < 3; j++) acc += H[i][j] * Vv[j][k];
                u[i] = acc; nrm += acc * acc;
            }
            nrm = sqrt(nrm);
            if (nrm < 1e-300) nrm = 1e-300;
            for (int i = 0; i < 3; i++) U[i][k] = u[i] / nrm;
        }
        double r[3][3];
        for (int i = 0; i < 3; i++)
            for (int j = 0; j < 3; j++) {
                double acc = 0;
                for (int k = 0; k < 3; k++) acc += Vv[i][k] * U[j][k];
                r[i][j] = acc;
            }
        double det = r[0][0] * (r[1][1] * r[2][2] - r[1][2] * r[2][1])
                   - r[0][1] * (r[1][0] * r[2][2] - r[1][2] * r[2][0])
                   + r[0][2] * (r[1][0] * r[2][1] - r[1][1] * r[2][0]);
        if (det < 0.0) {
            for (int i = 0; i < 3; i++)
                for (int j = 0; j < 3; j++)
                    r[i][j] -= 2.0 * Vv[i][2] * U[j][2];
        }
        double smean[3] = {(double)res[0], (double)res[1], (double)res[2]};
        double cmean[3] = {(double)res[3], (double)res[4], (double)res[5]};
        for (int i = 0; i < 3; i++)
            for (int j = 0; j < 3; j++)
                out[b * 9 + i * 3 + j] = (float)r[i][j];
        for (int i = 0; i < 3; i++) {
            double acc = cmean[i];
            for (int j = 0; j < 3; j++) acc -= r[i][j] * smean[j];
            out[B_ * 9 + b * 3 + i] = (float)acc;
        }
    }
}

// ---------------------------------------------------------------------------
extern "C" void kernel_launch(void* const* d_in, const int* in_sizes, int n_in,
                              void* d_out, int out_size, void* d_ws, size_t ws_size,
                              hipStream_t stream)
{
    const float* srcE = (const float*)d_in[0];
    const float* tgtE = (const float*)d_in[1];
    const float* src  = (const float*)d_in[2];
    const float* tgt  = (const float*)d_in[3];
    float* out = (float*)d_out;
    char* ws = (char*)d_ws;

    const size_t szLH = (size_t)B_ * N_ * N_ * sizeof(__half);   // 128 MiB
    size_t off = szLH;
    float* rzbuf  = (float*)(ws + off); off += (size_t)B_ * N_ * sizeof(float);
    float* topv   = (float*)(ws + off); off += (size_t)B_ * N_ * TOPK * sizeof(float);
    int*   topc   = (int*)(ws + off);   off += (size_t)B_ * N_ * TOPK * sizeof(int);
    float* colsum = (float*)(ws + off); off += (size_t)B_ * N_ * sizeof(float);
    int*   mrow   = (int*)(ws + off);   off += 1024;
    int*   mcol   = (int*)(ws + off);
    __half* lhalf = (__half*)ws;

    hipMemsetAsync(colsum, 0, (size_t)B_ * N_ * sizeof(float), stream);

    gemm6<<<dim3(N_ / RT, B_), 256, 0, stream>>>(srcE, tgtE, rzbuf, topv, topc, lhalf);
    colsum2<<<dim3(N_ / 512, 8, B_), 256, 0, stream>>>(lhalf, rzbuf, colsum);
    match2<<<B_, 256, 0, stream>>>(topv, topc, mrow, mcol);
    finish_kernel<<<B_, 256, 0, stream>>>(src, tgt, colsum, mrow, mcol, out);
}